// Round 23
// baseline (70.122 us; speedup 1.0000x reference)
//
#include <hip/hip_runtime.h>

#define Cc 256
#define Hh 96
#define Ww 128
#define CH_STRIDE (Hh * Ww)   // 12288 floats per channel plane
#define ROWS 16               // TH=8 output rows + 8 halo
#define SCOLS 24              // staged cols: w0-4 .. w0+19 (only band-used cols)
#define CSL  48               // shorts per cell: 96B (16B-aligned slots)
#define CELLS_PER_ROW 24      // packed; logical col 24..31 aliases next row / pad
#define BUF_SHORTS 19200      // 400 cells * 48 (>= 15*24+31+1, padded)

typedef __attribute__((ext_vector_type(8))) short bf16x8;  // 8 bf16 in 4 VGPRs
typedef __attribute__((ext_vector_type(4))) float f32x4;

// bijective within each 4-col group: spreads 96B-stride writes over 4 start banks
#define CPHYS(c) (((c) & ~3) | (((c) + ((c) >> 2)) & 3))

static __device__ __forceinline__ unsigned cvt_pk(float lo, float hi) {
  unsigned r;
  asm("v_cvt_pk_bf16_f32 %0, %1, %2" : "=v"(r) : "v"(lo), "v"(hi));
  return r;  // D[15:0]=bf16(lo), D[31:16]=bf16(hi)
}

#define FCOMP(v, cc) ((cc) == 0 ? (v).x : (cc) == 1 ? (v).y : (cc) == 2 ? (v).z : (v).w)

// vectorized x2 prefetch of chunk cx: 8 channels x float4-of-w
#define PF_LOAD(pf, cx)                                               \
  do {                                                                \
    const size_t cb_ = (size_t)(cx) * 32 * CH_STRIDE;                 \
    _Pragma("unroll")                                                 \
    for (int j = 0; j < 8; ++j)                                       \
      pf[j] = sok ? *(const float4*)(sptr + cb_ + (size_t)j * CH_STRIDE) \
                  : make_float4(0.f, 0.f, 0.f, 0.f);                  \
  } while (0)

// write 4 cells (logical c0..c0+3, CPHYS-swizzled) into buffer `bs`
#define LDS_WRITE(pf, bs)                                             \
  do {                                                                \
    _Pragma("unroll")                                                 \
    for (int cc = 0; cc < 4; ++cc) {                                  \
      uint4 pk;                                                       \
      pk.x = cvt_pk(FCOMP(pf[0], cc), FCOMP(pf[1], cc));              \
      pk.y = cvt_pk(FCOMP(pf[2], cc), FCOMP(pf[3], cc));              \
      pk.z = cvt_pk(FCOMP(pf[4], cc), FCOMP(pf[5], cc));              \
      pk.w = cvt_pk(FCOMP(pf[6], cc), FCOMP(pf[7], cc));              \
      *(uint4*)(&x2s[(bs) * BUF_SHORTS + wbase                        \
                     + CPHYS(4 * ug + cc) * CSL]) = pk;               \
    }                                                                 \
  } while (0)

#define COMPUTE(af, bs)                                               \
  do {                                                                \
    _Pragma("unroll")                                                 \
    for (int di = 0; di < 9; ++di) {                                  \
      const int rb_ = (bs) * BUF_SHORTS + (wv + di) * (CELLS_PER_ROW * CSL); \
      _Pragma("unroll")                                               \
      for (int t = 0; t < 2; ++t) {                                   \
        const bf16x8 bf_ = *(const bf16x8*)(&x2s[rb_ + rd[t]]);       \
        acc[di][t] = __builtin_amdgcn_mfma_f32_16x16x32_bf16(         \
            af, bf_, acc[di][t], 0, 0, 0);                            \
      }                                                               \
    }                                                                 \
  } while (0)

// corr[m=w][n=w'] via mfma_f32_16x16x32_bf16 (layouts verified PASS r12..r21):
//   A lane l: x1[m=l&15][k=8*(l>>4)+j];  B lane l: x2[k][n=l&15]
//   D lane l, reg q: row m=(l>>4)*4+q, col n=l&15
__global__ __launch_bounds__(512)
void corr_mfma(const float* __restrict__ x1, const float* __restrict__ x2,
               float* __restrict__ out) {
  __shared__ __align__(16) unsigned short x2s[2 * BUF_SHORTS];  // 76800 B

  const int tid  = threadIdx.x;
  const int bid  = blockIdx.x;
  // XCD-chunked swizzle (proven r9): 768 = 8 XCDs * 96 contiguous
  const int sbid = (bid & 7) * 96 + (bid >> 3);

  const int wt  = sbid & 7;          // w-tile
  const int hgb = sbid >> 3;         // b*12 + hg
  const int hg  = hgb % 12;
  const int b   = hgb / 12;
  const int h0  = hg * 8;
  const int w0  = wt * 16;

  const int wv   = tid >> 6;         // wave 0..7 -> h = h0+wv
  const int lane = tid & 63;
  const int n16  = lane & 15;
  const int kgrp = lane >> 4;
  const int h    = h0 + wv;

  // ---- staging geometry: 384 units = 4 chg x 16 rows x 6 col-groups ----
  const bool stager = (tid < 384);
  const int ug   = tid % 6;               // col group -> cols 4g..4g+3
  const int ur   = (tid / 6) % 16;        // staged row
  const int uchg = tid / 96;              // channel group (8 ch)
  const int gh   = h0 - 4 + ur;
  const int gw0  = w0 - 4 + 4 * ug;       // 4-aligned (16B)
  const bool sok = stager & (gh >= 0) & (gh < Hh) & (gw0 >= 0) & (gw0 + 3 < Ww);
  const int ghc  = sok ? gh : 0;
  const int gwc  = sok ? gw0 : 0;
  const float* sptr = x2 + ((size_t)(b * Cc + uchg * 8) * Hh + ghc) * Ww + gwc;
  const int wbase = ur * (CELLS_PER_ROW * CSL) + uchg * 8;  // + CPHYS(c)*CSL per cc

  // read offsets per t-tile (CPHYS-swizzled col, ch slot = kgrp)
  int rd[2];
#pragma unroll
  for (int t = 0; t < 2; ++t) {
    const int col = 16 * t + n16;
    rd[t] = CPHYS(col) * CSL + kgrp * 8;
  }

  // A element base: x1[b][kgrp*8 + j][h][w0 + n16]
  const float* pA = x1 + ((size_t)b * Cc * Hh + h) * Ww + (w0 + n16)
                       + (size_t)kgrp * 8 * CH_STRIDE;

  f32x4 acc[9][2];
#pragma unroll
  for (int di = 0; di < 9; ++di)
#pragma unroll
    for (int t = 0; t < 2; ++t) acc[di][t] = (f32x4){0.f, 0.f, 0.f, 0.f};

  // ---- prologue: stage chunk 0 into buf0; start chunk 1 prefetch ----
  float4 pf[8];
  if (stager) {
    PF_LOAD(pf, 0);
    LDS_WRITE(pf, 0);
    PF_LOAD(pf, 1);
  }
  __syncthreads();

  for (int ci = 0; ci < 8; ++ci) {
    const int bs = ci & 1;
    // A fragment (inline; stall overlaps across waves — r21 showed prefetch neutral)
    float pa[8];
    {
      const float* pAc = pA + (size_t)(ci * 32) * CH_STRIDE;
#pragma unroll
      for (int j = 0; j < 8; ++j) pa[j] = pAc[(size_t)j * CH_STRIDE];
    }
    bf16x8 af;
    {
      union { unsigned u[4]; bf16x8 v; } ux;
      ux.u[0] = cvt_pk(pa[0], pa[1]);
      ux.u[1] = cvt_pk(pa[2], pa[3]);
      ux.u[2] = cvt_pk(pa[4], pa[5]);
      ux.u[3] = cvt_pk(pa[6], pa[7]);
      af = ux.v;
    }

    // compute current buffer FIRST (no dependency on this chunk's staging)...
    COMPUTE(af, bs);

    // ...then stage next chunk into the other buffer (vmcnt stall sits after
    // our MFMAs, overlapped by other waves' compute), and issue chunk ci+2
    if (ci < 7) {
      if (stager) {
        LDS_WRITE(pf, bs ^ 1);
        if (ci < 6) PF_LOAD(pf, ci + 2);
      }
    }
    __syncthreads();  // one barrier per chunk: C(bs) done everywhere + W(bs^1) visible
  }

  // ---- epilogue: extract 9-band, scale, predicated scattered stores ----
  const float scale = 1.0f / (float)Cc;
#pragma unroll
  for (int di = 0; di < 9; ++di) {
#pragma unroll
    for (int t = 0; t < 2; ++t) {
#pragma unroll
      for (int q = 0; q < 4; ++q) {
        const int m  = kgrp * 4 + q;         // output w-offset in tile
        const int dj = 16 * t + n16 - m;     // band position
        if (dj >= 0 && dj <= 8) {
          out[(((size_t)b * 81 + di * 9 + dj) * Hh + h) * Ww + (w0 + m)]
              = acc[di][t][q] * scale;
        }
      }
    }
  }
}

extern "C" void kernel_launch(void* const* d_in, const int* in_sizes, int n_in,
                              void* d_out, int out_size, void* d_ws, size_t ws_size,
                              hipStream_t stream) {
  const float* x1 = (const float*)d_in[0];
  const float* x2 = (const float*)d_in[1];
  float* out = (float*)d_out;
  // 8 b * 12 hgroups * 8 wt = 768 blocks * 8 waves
  corr_mfma<<<768, 512, 0, stream>>>(x1, x2, out);
}

// Round 24
// 61.150 us; speedup vs baseline: 1.1467x; 1.1467x over previous
//
#include <hip/hip_runtime.h>

#define Cc 256
#define Hh 96
#define Ww 128
#define CH_STRIDE (Hh * Ww)   // 12288 floats per channel plane
#define ROWS 16               // TH=8 output rows + 8 halo
#define CSL  48               // shorts per cell: 96B (16B-aligned slots)
#define CELLS_PER_ROW 24      // packed (r23-validated); col 24..31 aliases = garbage -> dj>8 only
#define BUF_SHORTS 19200      // 400 cells * 48 (row15 col31 reach = 18751 < 19200)

typedef __attribute__((ext_vector_type(8))) short bf16x8;  // 8 bf16 in 4 VGPRs
typedef __attribute__((ext_vector_type(4))) float f32x4;

// bijective within each 4-col group: spreads 96B-stride writes over 4 start banks
#define CPHYS(c) (((c) & ~3) | (((c) + ((c) >> 2)) & 3))

static __device__ __forceinline__ unsigned cvt_pk(float lo, float hi) {
  unsigned r;
  asm("v_cvt_pk_bf16_f32 %0, %1, %2" : "=v"(r) : "v"(lo), "v"(hi));
  return r;  // D[15:0]=bf16(lo), D[31:16]=bf16(hi)
}

#define FCOMP(v, cc) ((cc) == 0 ? (v).x : (cc) == 1 ? (v).y : (cc) == 2 ? (v).z : (v).w)

// vectorized x2 prefetch of chunk cx: 8 channels x float4-of-w
#define PF_LOAD(pf, cx)                                               \
  do {                                                                \
    const size_t cb_ = (size_t)(cx) * 32 * CH_STRIDE;                 \
    _Pragma("unroll")                                                 \
    for (int j = 0; j < 8; ++j)                                       \
      pf[j] = sok ? *(const float4*)(sptr + cb_ + (size_t)j * CH_STRIDE) \
                  : make_float4(0.f, 0.f, 0.f, 0.f);                  \
  } while (0)

// write 4 cells (logical c0..c0+3, CPHYS-swizzled)
#define LDS_WRITE(pf)                                                 \
  do {                                                                \
    _Pragma("unroll")                                                 \
    for (int cc = 0; cc < 4; ++cc) {                                  \
      uint4 pk;                                                       \
      pk.x = cvt_pk(FCOMP(pf[0], cc), FCOMP(pf[1], cc));              \
      pk.y = cvt_pk(FCOMP(pf[2], cc), FCOMP(pf[3], cc));              \
      pk.z = cvt_pk(FCOMP(pf[4], cc), FCOMP(pf[5], cc));              \
      pk.w = cvt_pk(FCOMP(pf[6], cc), FCOMP(pf[7], cc));              \
      *(uint4*)(&x2s[wbase + CPHYS(4 * ug + cc) * CSL]) = pk;         \
    }                                                                 \
  } while (0)

// corr[m=w][n=w'] via mfma_f32_16x16x32_bf16 (layouts verified PASS r12..r23):
//   A lane l: x1[m=l&15][k=8*(l>>4)+j];  B lane l: x2[k][n=l&15]
//   D lane l, reg q: row m=(l>>4)*4+q, col n=l&15
__global__ __launch_bounds__(512)
void corr_mfma(const float* __restrict__ x1, const float* __restrict__ x2,
               float* __restrict__ out) {
  __shared__ __align__(16) unsigned short x2s[BUF_SHORTS];  // 38400 B -> 4 blocks/CU

  const int tid  = threadIdx.x;
  const int bid  = blockIdx.x;
  // XCD-chunked swizzle (proven r9): 768 = 8 XCDs * 96 contiguous
  const int sbid = (bid & 7) * 96 + (bid >> 3);

  const int wt  = sbid & 7;          // w-tile
  const int hgb = sbid >> 3;         // b*12 + hg
  const int hg  = hgb % 12;
  const int b   = hgb / 12;
  const int h0  = hg * 8;
  const int w0  = wt * 16;

  const int wv   = tid >> 6;         // wave 0..7 -> h = h0+wv
  const int lane = tid & 63;
  const int n16  = lane & 15;
  const int kgrp = lane >> 4;
  const int h    = h0 + wv;

  // ---- staging geometry: 384 units = 4 chg x 16 rows x 6 col-groups ----
  const bool stager = (tid < 384);
  const int ug   = tid % 6;               // col group -> cols 4g..4g+3
  const int ur   = (tid / 6) % 16;        // staged row
  const int uchg = tid / 96;              // channel group (8 ch)
  const int gh   = h0 - 4 + ur;
  const int gw0  = w0 - 4 + 4 * ug;       // 4-aligned (16B)
  const bool sok = stager & (gh >= 0) & (gh < Hh) & (gw0 >= 0) & (gw0 + 3 < Ww);
  const int ghc  = sok ? gh : 0;
  const int gwc  = sok ? gw0 : 0;
  const float* sptr = x2 + ((size_t)(b * Cc + uchg * 8) * Hh + ghc) * Ww + gwc;
  const int wbase = ur * (CELLS_PER_ROW * CSL) + uchg * 8;  // + CPHYS(c)*CSL per cc

  // read offsets per t-tile (CPHYS-swizzled col, ch slot = kgrp)
  int rd[2];
#pragma unroll
  for (int t = 0; t < 2; ++t) {
    const int col = 16 * t + n16;
    rd[t] = CPHYS(col) * CSL + kgrp * 8;
  }

  // A element base: x1[b][kgrp*8 + j][h][w0 + n16]
  const float* pA = x1 + ((size_t)b * Cc * Hh + h) * Ww + (w0 + n16)
                       + (size_t)kgrp * 8 * CH_STRIDE;

  f32x4 acc[9][2];
#pragma unroll
  for (int di = 0; di < 9; ++di)
#pragma unroll
    for (int t = 0; t < 2; ++t) acc[di][t] = (f32x4){0.f, 0.f, 0.f, 0.f};

  // ---- T14 prologue: prefetch chunk 0 ----
  float4 pf[8];
  if (stager) PF_LOAD(pf, 0);

  for (int ci = 0; ci < 8; ++ci) {
    __syncthreads();  // previous chunk's ds_reads done before overwrite

    // A loads for current chunk: issue early, consumed after LDS write
    float pa[8];
    {
      const float* pAc = pA + (size_t)(ci * 32) * CH_STRIDE;
#pragma unroll
      for (int j = 0; j < 8; ++j) pa[j] = pAc[(size_t)j * CH_STRIDE];
    }

    if (stager) LDS_WRITE(pf);

    // A fragment
    bf16x8 af;
    {
      union { unsigned u[4]; bf16x8 v; } ux;
      ux.u[0] = cvt_pk(pa[0], pa[1]);
      ux.u[1] = cvt_pk(pa[2], pa[3]);
      ux.u[2] = cvt_pk(pa[4], pa[5]);
      ux.u[3] = cvt_pk(pa[6], pa[7]);
      af = ux.v;
    }

    // prefetch NEXT chunk (in flight across barrier + compute)
    if (stager && ci < 7) PF_LOAD(pf, ci + 1);

    __syncthreads();  // LDS ready

    // branch-free compute: 18 ds_read_b128 + 18 MFMA per wave
#pragma unroll
    for (int di = 0; di < 9; ++di) {
      const int rb_ = (wv + di) * (CELLS_PER_ROW * CSL);
#pragma unroll
      for (int t = 0; t < 2; ++t) {
        const bf16x8 bf_ = *(const bf16x8*)(&x2s[rb_ + rd[t]]);
        acc[di][t] = __builtin_amdgcn_mfma_f32_16x16x32_bf16(af, bf_, acc[di][t], 0, 0, 0);
      }
    }
  }

  // ---- epilogue: extract 9-band, scale, predicated scattered stores ----
  const float scale = 1.0f / (float)Cc;
#pragma unroll
  for (int di = 0; di < 9; ++di) {
#pragma unroll
    for (int t = 0; t < 2; ++t) {
#pragma unroll
      for (int q = 0; q < 4; ++q) {
        const int m  = kgrp * 4 + q;         // output w-offset in tile
        const int dj = 16 * t + n16 - m;     // band position
        if (dj >= 0 && dj <= 8) {
          out[(((size_t)b * 81 + di * 9 + dj) * Hh + h) * Ww + (w0 + m)]
              = acc[di][t][q] * scale;
        }
      }
    }
  }
}

extern "C" void kernel_launch(void* const* d_in, const int* in_sizes, int n_in,
                              void* d_out, int out_size, void* d_ws, size_t ws_size,
                              hipStream_t stream) {
  const float* x1 = (const float*)d_in[0];
  const float* x2 = (const float*)d_in[1];
  float* out = (float*)d_out;
  // 8 b * 12 hgroups * 8 wt = 768 blocks * 8 waves
  corr_mfma<<<768, 512, 0, stream>>>(x1, x2, out);
}